// Round 15
// baseline (179.264 us; speedup 1.0000x reference)
//
#include <hip/hip_runtime.h>

static constexpr int   N_NODES = 50000;
static constexpr int   N_EDGES = 600000;
static constexpr int   D       = 128;
static constexpr int   CAP     = 64;    // slots per node; P(deg>64) ~ e^-40 for this graph
static constexpr float ALPHA   = 0.1f;
static constexpr float BETA    = 0.22314355131420976f;  // log(1.25)
static constexpr float OMB     = 1.0f - BETA;           // (1-beta)

static constexpr int TMF = 32;                           // merged-kernel tile rows
static constexpr int NTF = (N_NODES + TMF - 1) / TMF;    // 1563
static constexpr int HP  = 132;                          // padded h_sh row stride (floats)

typedef __attribute__((ext_vector_type(8))) short short8;   // 8 bf16 (4 VGPRs)
typedef __attribute__((ext_vector_type(4))) float f32x4;

// fp32 -> bf16 with round-to-nearest-even (exact shift back on read)
__device__ __forceinline__ unsigned int f2bf(float f) {
    unsigned int u = __float_as_uint(f);
    return (u + 0x7FFFu + ((u >> 16) & 1u)) >> 16;
}
__device__ __forceinline__ float bf2f(unsigned int b) {
    return __uint_as_float(b << 16);
}
// degree -> symmetric-norm factor (bit-identical rsqrtf everywhere)
__device__ __forceinline__ float deg2norm(int d) {
    return rsqrtf(fmaxf((float)d, 1.0f));
}

// ---------------- convert feat->bf16 + W->bf16^T + zero cnt (round-13 exact) ----------------
__global__ void conv_kernel(const float* __restrict__ feat,
                            unsigned short* __restrict__ featb,
                            const float* __restrict__ W,
                            unsigned short* __restrict__ wbt,   // [col][k] bf16
                            int* __restrict__ cnt) {
    const int tid = blockIdx.x * blockDim.x + threadIdx.x;
    if (tid * 4 < N_NODES)
        *reinterpret_cast<int4*>(cnt + tid * 4) = make_int4(0, 0, 0, 0);
    // W^T bf16: 16384 elems, 8 per thread (tid < 2048)
    if (tid * 8 < D * D) {
        const int c  = (tid * 8) >> 7;          // output col
        const int k0 = (tid * 8) & 127;
        unsigned short w8[8];
        #pragma unroll
        for (int j = 0; j < 8; ++j)
            w8[j] = (unsigned short)f2bf(W[(size_t)(k0 + j) * D + c]);
        #pragma unroll
        for (int j = 0; j < 8; ++j)
            wbt[(size_t)c * D + k0 + j] = w8[j];
    }
    const size_t e0 = (size_t)tid * 16;
    if (e0 < (size_t)N_NODES * D) {
        const float* p = feat + e0;
        #pragma unroll
        for (int q = 0; q < 2; ++q) {
            float4 a = *reinterpret_cast<const float4*>(p + q * 8);
            float4 b = *reinterpret_cast<const float4*>(p + q * 8 + 4);
            uint4 o;
            o.x = f2bf(a.x) | (f2bf(a.y) << 16);
            o.y = f2bf(a.z) | (f2bf(a.w) << 16);
            o.z = f2bf(b.x) | (f2bf(b.y) << 16);
            o.w = f2bf(b.z) | (f2bf(b.w) << 16);
            *reinterpret_cast<uint4*>(featb + e0 + q * 8) = o;
        }
    }
}

// ---------------- slot fill, pure 1 edge/thread (round-9 exact) ----------------
__global__ void fill_kernel(const int* __restrict__ src, const int* __restrict__ dst,
                            int* __restrict__ cnt, int* __restrict__ slots) {
    const int tid = blockIdx.x * blockDim.x + threadIdx.x;
    if (tid < N_EDGES) {
        int s = src[tid];
        int d = dst[tid];
        int p = atomicAdd(&cnt[d], 1);
        if (p < CAP) slots[d * CAP + p] = s;
    }
}

// ---------------- merged gather + epilogue + MFMA GEMM ----------------
// Round-14 structure; phase-A change: the per-batch __shfl distribution
// (8 ds_permute per batch -> ~14 us of DS-pipe time across the kernel, a
// co-limiter with VALU) is replaced by a wave-private LDS (s,n) table:
// setup writes each lane's (slot, norm) int2 once; each batch reads its 4
// pairs with uniform-per-half ds_read_b64 broadcasts (4 DS ops, s and n
// delivered together). Same values, same summation order -> bit-identical.
__global__ __launch_bounds__(512, 4) void gf2_kernel(
    const unsigned short* __restrict__ featb, const int* __restrict__ slots,
    const int* __restrict__ cnt_arr, const float* __restrict__ feat_0,
    const unsigned short* __restrict__ wbt,   // W^T bf16 [col][k]
    const float* __restrict__ bias,
    float* __restrict__ out)
{
    __shared__ float h_sh[TMF * HP];   // 32 x 132 floats = 16.9 KB
    __shared__ int2  sn_sh[8][CAP];    // per-wave (slot, norm) table: 4 KB

    const int t    = threadIdx.x;
    const int wave = t >> 6;           // 0..7
    const int lane = t & 63;
    const int half = lane >> 5;
    const int l32  = lane & 31;
    const int row0 = blockIdx.x * TMF;
    const unsigned short* __restrict__ fcol = featb + (size_t)l32 * 4;

    // ---- Phase A: 4 nodes per wave ----
    #pragma unroll 1
    for (int i = 0; i < 4; ++i) {
        const int lr   = wave * 4 + i;     // local row 0..31
        const int node = row0 + lr;
        if (node < N_NODES) {
            const int base = node * CAP;
            const int cnt  = min(cnt_arr[node], CAP);

            // stage (slot, norm) for edge 'lane' into the wave's LDS table
            int2 sn = make_int2(0, 0);     // n = 0.0f beyond cnt
            if (lane < cnt) {
                int s = slots[base + lane];
                sn = make_int2(s, __float_as_int(deg2norm(cnt_arr[s])));
            }
            sn_sh[wave][lane] = sn;        // wave-private; ds-order enforced by
                                           // LDS aliasing (same object) + lgkmcnt

            float4 acc = make_float4(0.f, 0.f, 0.f, 0.f);
            const int nb = (cnt + 7) >> 3;
            for (int b = 0; b < nb; ++b) {
                const int j = b * 8 + half;            // uniform per half
                int2 c0 = sn_sh[wave][j];              // broadcast ds_read_b64
                int2 c1 = sn_sh[wave][j + 2];
                int2 c2 = sn_sh[wave][j + 4];
                int2 c3 = sn_sh[wave][j + 6];
                float n0 = __int_as_float(c0.y), n1 = __int_as_float(c1.y);
                float n2 = __int_as_float(c2.y), n3 = __int_as_float(c3.y);
                ushort4 u0 = *reinterpret_cast<const ushort4*>(fcol + (size_t)c0.x * D);
                ushort4 u1 = *reinterpret_cast<const ushort4*>(fcol + (size_t)c1.x * D);
                ushort4 u2 = *reinterpret_cast<const ushort4*>(fcol + (size_t)c2.x * D);
                ushort4 u3 = *reinterpret_cast<const ushort4*>(fcol + (size_t)c3.x * D);
                acc.x += bf2f(u0.x)*n0 + bf2f(u1.x)*n1 + bf2f(u2.x)*n2 + bf2f(u3.x)*n3;
                acc.y += bf2f(u0.y)*n0 + bf2f(u1.y)*n1 + bf2f(u2.y)*n2 + bf2f(u3.y)*n3;
                acc.z += bf2f(u0.z)*n0 + bf2f(u1.z)*n1 + bf2f(u2.z)*n2 + bf2f(u3.z)*n3;
                acc.w += bf2f(u0.w)*n0 + bf2f(u1.w)*n1 + bf2f(u2.w)*n2 + bf2f(u3.w)*n3;
            }
            acc.x += __shfl_xor(acc.x, 32);
            acc.y += __shfl_xor(acc.y, 32);
            acc.z += __shfl_xor(acc.z, 32);
            acc.w += __shfl_xor(acc.w, 32);
            if (half == 0) {
                float nm = deg2norm(cnt_arr[node]) * (1.0f - ALPHA);
                float4 f0 = *reinterpret_cast<const float4*>(
                                feat_0 + (size_t)node * D + l32 * 4);
                float4 h;
                h.x = acc.x * nm + f0.x * ALPHA;
                h.y = acc.y * nm + f0.y * ALPHA;
                h.z = acc.z * nm + f0.z * ALPHA;
                h.w = acc.w * nm + f0.w * ALPHA;
                *reinterpret_cast<float4*>(&h_sh[lr * HP + l32 * 4]) = h;
            }
        } else if (half == 0) {
            *reinterpret_cast<float4*>(&h_sh[lr * HP + l32 * 4]) =
                make_float4(0.f, 0.f, 0.f, 0.f);
        }
    }
    __syncthreads();   // the only barrier

    // ---- Phase B: MFMA GEMM, wave w -> 16-col strip ----
    const int lrow = lane & 15;        // A row / B col / D col
    const int lgrp = lane >> 4;        // k-group (and D row group)
    const int col  = wave * 16 + lrow; // wave's column strip

    // B fragments: 4 k-blocks, loaded once from L2-hot wbt
    short8 bfrag[4];
    #pragma unroll
    for (int kb = 0; kb < 4; ++kb)
        bfrag[kb] = *reinterpret_cast<const short8*>(
            wbt + (size_t)col * D + kb * 32 + lgrp * 8);

    f32x4 acc0 = (f32x4){0.f, 0.f, 0.f, 0.f};
    f32x4 acc1 = (f32x4){0.f, 0.f, 0.f, 0.f};

    #pragma unroll
    for (int rt = 0; rt < 2; ++rt) {
        // A fragments: h (fp32 LDS) -> bf16 in-register
        const float* hp = &h_sh[(rt * 16 + lrow) * HP];
        short8 afrag[4];
        #pragma unroll
        for (int kb = 0; kb < 4; ++kb) {
            float4 x = *reinterpret_cast<const float4*>(hp + kb * 32 + lgrp * 8);
            float4 y = *reinterpret_cast<const float4*>(hp + kb * 32 + lgrp * 8 + 4);
            short8 a;
            a[0] = (short)f2bf(x.x); a[1] = (short)f2bf(x.y);
            a[2] = (short)f2bf(x.z); a[3] = (short)f2bf(x.w);
            a[4] = (short)f2bf(y.x); a[5] = (short)f2bf(y.y);
            a[6] = (short)f2bf(y.z); a[7] = (short)f2bf(y.w);
            afrag[kb] = a;
        }
        if (rt == 0) {
            #pragma unroll
            for (int kb = 0; kb < 4; ++kb)
                acc0 = __builtin_amdgcn_mfma_f32_16x16x32_bf16(
                    afrag[kb], bfrag[kb], acc0, 0, 0, 0);
        } else {
            #pragma unroll
            for (int kb = 0; kb < 4; ++kb)
                acc1 = __builtin_amdgcn_mfma_f32_16x16x32_bf16(
                    afrag[kb], bfrag[kb], acc1, 0, 0, 0);
        }
    }

    // epilogue: D layout col=lane&15, row=lgrp*4+reg
    const float bv = bias[col];
    #pragma unroll
    for (int reg = 0; reg < 4; ++reg) {
        {
            const int lr   = lgrp * 4 + reg;          // rt=0 rows 0..15
            const int node = row0 + lr;
            if (node < N_NODES) {
                float h = h_sh[lr * HP + col];
                out[(size_t)node * D + col] = OMB * h + BETA * acc0[reg] + bv;
            }
        }
        {
            const int lr   = 16 + lgrp * 4 + reg;     // rt=1 rows 16..31
            const int node = row0 + lr;
            if (node < N_NODES) {
                float h = h_sh[lr * HP + col];
                out[(size_t)node * D + col] = OMB * h + BETA * acc1[reg] + bv;
            }
        }
    }
}

extern "C" void kernel_launch(void* const* d_in, const int* in_sizes, int n_in,
                              void* d_out, int out_size, void* d_ws, size_t ws_size,
                              hipStream_t stream) {
    const float* feat   = (const float*)d_in[0];
    const float* feat_0 = (const float*)d_in[1];
    const float* W      = (const float*)d_in[2];
    const float* bias   = (const float*)d_in[3];
    const int*   src    = (const int*)d_in[4];
    const int*   dst    = (const int*)d_in[5];
    float*       out    = (float*)d_out;

    // workspace: cnt (200 KB) | slots (12.8 MB) | featb (12.8 MB) | wbt (32 KB)
    char* ws = (char*)d_ws;
    int*   cnt   = (int*)ws;            ws += (size_t)N_NODES * 4;
    int*   slots = (int*)ws;            ws += (size_t)N_NODES * CAP * 4;
    unsigned short* featb = (unsigned short*)ws;  ws += (size_t)N_NODES * D * 2;
    unsigned short* wbt   = (unsigned short*)ws;

    // 1) convert feat->bf16, W->bf16^T, zero cnt
    conv_kernel<<<(N_NODES * (D / 16) + 255) / 256, 256, 0, stream>>>(
        feat, featb, W, wbt, cnt);

    // 2) slot fill
    fill_kernel<<<(N_EDGES + 255) / 256, 256, 0, stream>>>(src, dst, cnt, slots);

    // 3) merged gather + epilogue + MFMA GEMM (LDS (s,n) table replaces shfl)
    gf2_kernel<<<NTF, 512, 0, stream>>>(featb, slots, cnt, feat_0, wbt, bias, out);
}